// Round 6
// baseline (436.687 us; speedup 1.0000x reference)
//
#include <hip/hip_runtime.h>

#define N_NODES 100000
#define N_EDGES 1600000
#define C 128
#define NCLS 40
#define NBUCK 196   // ceil(100000/512)
#define BCAP 12288  // per-bucket edge capacity (mean 8192, +45 sigma)
#define NT_TILES 3125  // 100000/32

typedef _Float16 half8 __attribute__((ext_vector_type(8)));
typedef float f32x4 __attribute__((ext_vector_type(4)));
typedef float f32x16 __attribute__((ext_vector_type(16)));

// ================= bucketed CSR build =================

__global__ __launch_bounds__(256) void bucket_scatter_k(const int* __restrict__ src,
    const int* __restrict__ dst, int* __restrict__ bucket_cnt, int* __restrict__ bucketArr) {
  __shared__ int lh[NBUCK], lbase[NBUCK], lcur[NBUCK];
  int tid = threadIdx.x;
  for (int i = tid; i < NBUCK; i += 256) { lh[i] = 0; lcur[i] = 0; }
  __syncthreads();
  int base = blockIdx.x * 4096;
  int bmax = min(base + 4096, N_EDGES);
  // cache dst in registers across both passes (16 per thread)
  int dreg[16];
  int nk = 0;
  for (int e = base + tid; e < bmax; e += 256) dreg[nk++] = dst[e];
  for (int k = 0; k < nk; k++) atomicAdd(&lh[dreg[k] >> 9], 1);
  __syncthreads();
  for (int i = tid; i < NBUCK; i += 256)
    lbase[i] = lh[i] ? atomicAdd(&bucket_cnt[i], lh[i]) : 0;
  __syncthreads();
  nk = 0;
  for (int e = base + tid; e < bmax; e += 256) {
    int d = dreg[nk++];
    int b = d >> 9, loc = d & 511;
    int p = lbase[b] + atomicAdd(&lcur[b], 1);
    if (p < BCAP) bucketArr[(size_t)b * BCAP + p] = (src[e] << 9) | loc;
  }
}

// parallel exclusive scan over 196 bucket counts (1 block / 256 threads)
__global__ void bucket_scan_k(const int* __restrict__ bucket_cnt, int* __restrict__ bucket_base,
                              int* __restrict__ rp) {
  int tid = threadIdx.x;
  int v = (tid < NBUCK) ? min(bucket_cnt[tid], BCAP) : 0;
  int lane = tid & 63, wid = tid >> 6;
  int inc = v;
  for (int d = 1; d < 64; d <<= 1) { int y = __shfl_up(inc, d, 64); if (lane >= d) inc += y; }
  __shared__ int wsum[4];
  if (lane == 63) wsum[wid] = inc;
  __syncthreads();
  int woff = 0;
  for (int q = 0; q < wid; q++) woff += wsum[q];
  int ex = woff + inc - v;
  if (tid < NBUCK) bucket_base[tid] = ex;
  if (tid == NBUCK - 1) { bucket_base[NBUCK] = ex + v; rp[N_NODES] = ex + v; }
}

__global__ __launch_bounds__(256) void bucket_sort_k(const int* __restrict__ bucketArr,
    const int* __restrict__ bucket_cnt, const int* __restrict__ bucket_base,
    int* __restrict__ rp, int* __restrict__ csr) {
  __shared__ int hist[512], offs[512], curs[512];
  __shared__ int wpart[4];
  __shared__ int lsrc[BCAP];
  int b = blockIdx.x, tid = threadIdx.x;
  int cnt = min(bucket_cnt[b], BCAP);
  int base = bucket_base[b];
  for (int i = tid; i < 512; i += 256) hist[i] = 0;
  __syncthreads();
  for (int i = tid; i < cnt; i += 256)
    atomicAdd(&hist[bucketArr[(size_t)b * BCAP + i] & 511], 1);
  __syncthreads();
  int a0 = hist[2 * tid], a1 = hist[2 * tid + 1];
  int s = a0 + a1;
  int lane = tid & 63, wid = tid >> 6;
  int inc = s;
  for (int d = 1; d < 64; d <<= 1) { int y = __shfl_up(inc, d, 64); if (lane >= d) inc += y; }
  if (lane == 63) wpart[wid] = inc;
  __syncthreads();
  int woff = 0;
  for (int q = 0; q < wid; q++) woff += wpart[q];
  int ex = woff + inc - s;
  offs[2 * tid] = ex; offs[2 * tid + 1] = ex + a0;
  curs[2 * tid] = ex; curs[2 * tid + 1] = ex + a0;
  __syncthreads();
  for (int i = tid; i < 512; i += 256) {
    int gn = b * 512 + i;
    if (gn < N_NODES) rp[gn] = base + offs[i];
  }
  for (int i = tid; i < cnt; i += 256) {
    int packed = bucketArr[(size_t)b * BCAP + i];
    int p = atomicAdd(&curs[packed & 511], 1);
    lsrc[p] = packed >> 9;
  }
  __syncthreads();
  for (int i = tid; i < cnt; i += 256) csr[base + i] = lsrc[i];
}

// ================= fp32 -> fp16 convert / weight prep =================

__global__ __launch_bounds__(256) void f32_to_f16_k(const float* __restrict__ in,
                                                    _Float16* __restrict__ out) {
  int i = blockIdx.x * 256 + threadIdx.x;
  float4 v0 = *(const float4*)(in + (size_t)i * 8);
  float4 v1 = *(const float4*)(in + (size_t)i * 8 + 4);
  half8 o;
  o[0] = (_Float16)v0.x; o[1] = (_Float16)v0.y; o[2] = (_Float16)v0.z; o[3] = (_Float16)v0.w;
  o[4] = (_Float16)v1.x; o[5] = (_Float16)v1.y; o[6] = (_Float16)v1.z; o[7] = (_Float16)v1.w;
  *(half8*)(out + (size_t)i * 8) = o;
}

// WT[n][k] = f16( k<128 ? Ws[k][n] : Wn[k-128][n] )
__global__ void build_wt_k(const float* __restrict__ Ws, const float* __restrict__ Wn,
                           _Float16* __restrict__ WT) {
  int n = blockIdx.x, k = threadIdx.x;
  float v = (k < 128) ? Ws[k * 128 + n] : Wn[(k - 128) * 128 + n];
  WT[n * 256 + k] = (_Float16)v;
}

__global__ void build_wct_k(const float* __restrict__ Wc, const float* __restrict__ bc,
                            _Float16* __restrict__ WcT, float* __restrict__ bcf) {
  int c = blockIdx.x, k = threadIdx.x;
  float v = (c < NCLS) ? Wc[k * NCLS + c] : 0.f;
  WcT[c * C + k] = (_Float16)v;
  if (k == 0) bcf[c] = (c < NCLS) ? bc[c] : 0.f;
}

// ================= column-sharded mean aggregation =================
// 4 shards of 64B (32 f16). Shard pinned to an XCD pair via bid%8 so each
// XCD-pair's L2 only sees a 6.4MB slice of the feature table.
// Wave = 4 nodes; per node: 16 lanes = 4 edges (g) x 4 feat-lanes (lr, 8 f16).
// Reduction over g = 2 shuffle levels (xor 4, 8).

__global__ __launch_bounds__(256) void agg_mean_shard_k(const _Float16* __restrict__ feat,
    const int* __restrict__ rp, const int* __restrict__ csr, _Float16* __restrict__ out) {
  int bid = blockIdx.x;
  int shard = (bid & 7) >> 1;               // XCD pair
  int tile  = (bid >> 3) * 2 + (bid & 1);   // [0, 6250)
  int tid = threadIdx.x;
  int w = tid >> 6, lane = tid & 63;
  int nslot = lane >> 4;
  int g  = (lane >> 2) & 3;
  int lr = lane & 3;
  int node = tile * 16 + w * 4 + nslot;     // 6250*16 = 100000 exactly
  int beg = rp[node], end = rp[node + 1];
  const _Float16* fbase = feat + shard * 32 + lr * 8;
  float acc[8] = {}, acc2[8] = {};
  int j = beg;
  for (; j + 8 <= end; j += 8) {
    int e0 = csr[j + g];
    int e1 = csr[j + 4 + g];
    half8 v0 = *(const half8*)(fbase + (size_t)e0 * C);
    half8 v1 = *(const half8*)(fbase + (size_t)e1 * C);
#pragma unroll
    for (int q = 0; q < 8; q++) { acc[q] += (float)v0[q]; acc2[q] += (float)v1[q]; }
  }
  if (j + 4 <= end) {
    int e0 = csr[j + g];
    half8 v0 = *(const half8*)(fbase + (size_t)e0 * C);
#pragma unroll
    for (int q = 0; q < 8; q++) acc[q] += (float)v0[q];
    j += 4;
  }
  int rem = end - j;
  if (g < rem) {
    int e0 = csr[j + g];
    half8 v0 = *(const half8*)(fbase + (size_t)e0 * C);
#pragma unroll
    for (int q = 0; q < 8; q++) acc2[q] += (float)v0[q];
  }
#pragma unroll
  for (int q = 0; q < 8; q++) {
    float v = acc[q] + acc2[q];
    v += __shfl_xor(v, 4, 64);
    v += __shfl_xor(v, 8, 64);
    acc[q] = v;
  }
  if (g == 0) {
    float inv = 1.0f / fmaxf((float)(end - beg), 1.0f);
    half8 o;
#pragma unroll
    for (int q = 0; q < 8; q++) o[q] = (_Float16)(acc[q] * inv);
    *(half8*)(out + (size_t)node * C + shard * 32 + lr * 8) = o;
  }
}

// ================= weights-stationary fused SAGE GEMM =================

__global__ __launch_bounds__(256) void sage_gemm_ws_k(
    const _Float16* __restrict__ Xs, const _Float16* __restrict__ Xn,
    const _Float16* __restrict__ WT, const float* __restrict__ bias,
    _Float16* __restrict__ out) {
  __shared__ _Float16 cbuf[32][136];
  int tid = threadIdx.x, lane = tid & 63, wid = tid >> 6;
  int l31 = lane & 31, l5 = lane >> 5;
  int col0 = wid * 32;

  half8 b[16];
#pragma unroll
  for (int ks = 0; ks < 16; ks++)
    b[ks] = *(const half8*)(WT + (size_t)(col0 + l31) * 256 + ks * 16 + l5 * 8);
  float bcol = bias[col0 + l31];

  for (int t = blockIdx.x; t < NT_TILES; t += gridDim.x) {
    size_t row0 = (size_t)t * 32;
    half8 a[16];
#pragma unroll
    for (int ks = 0; ks < 8; ks++) {
      a[ks]     = *(const half8*)(Xs + (row0 + l31) * C + ks * 16 + l5 * 8);
      a[ks + 8] = *(const half8*)(Xn + (row0 + l31) * C + ks * 16 + l5 * 8);
    }
    f32x16 acc = {};
#pragma unroll
    for (int ks = 0; ks < 16; ks++)
      acc = __builtin_amdgcn_mfma_f32_32x32x16_f16(a[ks], b[ks], acc, 0, 0, 0);

    __syncthreads();
#pragma unroll
    for (int q = 0; q < 16; q++) {
      int row = (q & 3) + 8 * (q >> 2) + 4 * l5;
      float v = fmaxf(acc[q] + bcol, 0.f);
      cbuf[row][col0 + l31] = (_Float16)v;
    }
    __syncthreads();
#pragma unroll
    for (int p = 0; p < 2; p++) {
      int chunk = tid + p * 256;
      int r = chunk >> 4, cg = chunk & 15;
      half8 v = *(const half8*)&cbuf[r][cg * 8];
      *(half8*)(out + (row0 + r) * C + cg * 8) = v;
    }
  }
}

// ================= classifier via MFMA =================

__global__ __launch_bounds__(256) void classifier_mfma_k(const _Float16* __restrict__ h,
    const _Float16* __restrict__ WcT, const float* __restrict__ bcf, float* __restrict__ out) {
  __shared__ float cbuf[64][49];
  int tid = threadIdx.x, lane = tid & 63, wid = tid >> 6;
  int lr = lane & 15, lk = lane >> 4;
  int row0 = blockIdx.x * 64 + wid * 16;
  f32x4 acc[3] = {};
#pragma unroll
  for (int ks = 0; ks < 4; ks++) {
    half8 a = {};
    int r = row0 + lr;
    if (r < N_NODES) a = *(const half8*)(h + (size_t)r * C + ks * 32 + lk * 8);
#pragma unroll
    for (int nf = 0; nf < 3; nf++) {
      half8 bfr = *(const half8*)(WcT + (size_t)(nf * 16 + lr) * C + ks * 32 + lk * 8);
      acc[nf] = __builtin_amdgcn_mfma_f32_16x16x32_f16(a, bfr, acc[nf], 0, 0, 0);
    }
  }
#pragma unroll
  for (int nf = 0; nf < 3; nf++)
#pragma unroll
    for (int q = 0; q < 4; q++) {
      int c = nf * 16 + lr;
      cbuf[wid * 16 + lk * 4 + q][c] = acc[nf][q] + bcf[c];
    }
  __syncthreads();
  int row_blk0 = blockIdx.x * 64;
  for (int i = tid; i < 64 * NCLS; i += 256) {
    int r = i / NCLS, c = i - r * NCLS;
    int gr = row_blk0 + r;
    if (gr < N_NODES) out[(size_t)gr * NCLS + c] = cbuf[r][c];
  }
}

// ================= launch =================

extern "C" void kernel_launch(void* const* d_in, const int* in_sizes, int n_in,
                              void* d_out, int out_size, void* d_ws, size_t ws_size,
                              hipStream_t stream) {
  (void)in_sizes; (void)n_in; (void)out_size; (void)ws_size;
  const float* x   = (const float*)d_in[0];
  const int*   ei  = (const int*)d_in[1];
  const float* Ws1 = (const float*)d_in[2];
  const float* Wn1 = (const float*)d_in[3];
  const float* b1  = (const float*)d_in[4];
  const float* Ws2 = (const float*)d_in[5];
  const float* Wn2 = (const float*)d_in[6];
  const float* b2  = (const float*)d_in[7];
  const float* Wc  = (const float*)d_in[8];
  const float* bc  = (const float*)d_in[9];
  const int* src = ei;
  const int* dst = ei + N_EDGES;

  char* ws = (char*)d_ws;
  size_t off = 0;
  auto alloc = [&](size_t bytes) {
    void* p = ws + off;
    off = (off + bytes + 255) & ~(size_t)255;
    return p;
  };
  int*      bucket_cnt  = (int*)alloc((size_t)NBUCK * 4);
  int*      bucket_base = (int*)alloc((size_t)(NBUCK + 1) * 4);
  int*      bucketArr   = (int*)alloc((size_t)NBUCK * BCAP * 4);
  int*      rp          = (int*)alloc((size_t)(N_NODES + 1) * 4);
  int*      csr         = (int*)alloc((size_t)N_EDGES * 4);
  _Float16* hA          = (_Float16*)alloc((size_t)N_NODES * C * 2);
  _Float16* hB          = (_Float16*)alloc((size_t)N_NODES * C * 2);
  _Float16* hC          = (_Float16*)alloc((size_t)N_NODES * C * 2);
  _Float16* WT1         = (_Float16*)alloc((size_t)C * 256 * 2);
  _Float16* WT2         = (_Float16*)alloc((size_t)C * 256 * 2);
  _Float16* WcT         = (_Float16*)alloc((size_t)48 * C * 2);
  float*    bcf         = (float*)alloc(48 * 4);
  float* outf = (float*)d_out;

  hipMemsetAsync(bucket_cnt, 0, (size_t)NBUCK * 4, stream);
  bucket_scatter_k<<<(N_EDGES + 4095) / 4096, 256, 0, stream>>>(src, dst, bucket_cnt, bucketArr);
  bucket_scan_k<<<1, 256, 0, stream>>>(bucket_cnt, bucket_base, rp);
  bucket_sort_k<<<NBUCK, 256, 0, stream>>>(bucketArr, bucket_cnt, bucket_base, rp, csr);

  build_wt_k<<<C, 256, 0, stream>>>(Ws1, Wn1, WT1);
  build_wt_k<<<C, 256, 0, stream>>>(Ws2, Wn2, WT2);
  build_wct_k<<<48, C, 0, stream>>>(Wc, bc, WcT, bcf);
  f32_to_f16_k<<<(N_NODES * C / 8) / 256, 256, 0, stream>>>(x, hA);

  // layer 1
  agg_mean_shard_k<<<25000, 256, 0, stream>>>(hA, rp, csr, hB);
  sage_gemm_ws_k<<<782, 256, 0, stream>>>(hA, hB, WT1, b1, hC);
  // layer 2
  agg_mean_shard_k<<<25000, 256, 0, stream>>>(hC, rp, csr, hB);
  sage_gemm_ws_k<<<782, 256, 0, stream>>>(hC, hB, WT2, b2, hA);
  // classifier
  classifier_mfma_k<<<(N_NODES + 63) / 64, 256, 0, stream>>>(hA, WcT, bcf, outf);
}

// Round 7
// 413.642 us; speedup vs baseline: 1.0557x; 1.0557x over previous
//
#include <hip/hip_runtime.h>

#define N_NODES 100000
#define N_EDGES 1600000
#define C 128
#define NCLS 40
#define NBUCK 196   // ceil(100000/512)
#define BCAP 12288  // per-bucket edge capacity (mean 8192, +45 sigma)
#define NT_TILES 3125  // 100000/32
#define NB_FUSED 1024

typedef _Float16 half8 __attribute__((ext_vector_type(8)));
typedef float f32x4 __attribute__((ext_vector_type(4)));
typedef float f32x16 __attribute__((ext_vector_type(16)));

// ================= bucketed CSR build =================

__global__ __launch_bounds__(256) void bucket_scatter_k(const int* __restrict__ src,
    const int* __restrict__ dst, int* __restrict__ bucket_cnt, int* __restrict__ bucketArr) {
  __shared__ int lh[NBUCK], lbase[NBUCK], lcur[NBUCK];
  int tid = threadIdx.x;
  for (int i = tid; i < NBUCK; i += 256) { lh[i] = 0; lcur[i] = 0; }
  __syncthreads();
  int base = blockIdx.x * 4096;
  int bmax = min(base + 4096, N_EDGES);
  int dreg[16];
  int nk = 0;
  for (int e = base + tid; e < bmax; e += 256) dreg[nk++] = dst[e];
  for (int k = 0; k < nk; k++) atomicAdd(&lh[dreg[k] >> 9], 1);
  __syncthreads();
  for (int i = tid; i < NBUCK; i += 256)
    lbase[i] = lh[i] ? atomicAdd(&bucket_cnt[i], lh[i]) : 0;
  __syncthreads();
  nk = 0;
  for (int e = base + tid; e < bmax; e += 256) {
    int d = dreg[nk++];
    int b = d >> 9, loc = d & 511;
    int p = lbase[b] + atomicAdd(&lcur[b], 1);
    if (p < BCAP) bucketArr[(size_t)b * BCAP + p] = (src[e] << 9) | loc;
  }
}

__global__ void bucket_scan_k(const int* __restrict__ bucket_cnt, int* __restrict__ bucket_base,
                              int* __restrict__ rp) {
  int tid = threadIdx.x;
  int v = (tid < NBUCK) ? min(bucket_cnt[tid], BCAP) : 0;
  int lane = tid & 63, wid = tid >> 6;
  int inc = v;
  for (int d = 1; d < 64; d <<= 1) { int y = __shfl_up(inc, d, 64); if (lane >= d) inc += y; }
  __shared__ int wsum[4];
  if (lane == 63) wsum[wid] = inc;
  __syncthreads();
  int woff = 0;
  for (int q = 0; q < wid; q++) woff += wsum[q];
  int ex = woff + inc - v;
  if (tid < NBUCK) bucket_base[tid] = ex;
  if (tid == NBUCK - 1) { bucket_base[NBUCK] = ex + v; rp[N_NODES] = ex + v; }
}

__global__ __launch_bounds__(256) void bucket_sort_k(const int* __restrict__ bucketArr,
    const int* __restrict__ bucket_cnt, const int* __restrict__ bucket_base,
    int* __restrict__ rp, int* __restrict__ csr) {
  __shared__ int hist[512], offs[512], curs[512];
  __shared__ int wpart[4];
  __shared__ int lsrc[BCAP];
  int b = blockIdx.x, tid = threadIdx.x;
  int cnt = min(bucket_cnt[b], BCAP);
  int base = bucket_base[b];
  for (int i = tid; i < 512; i += 256) hist[i] = 0;
  __syncthreads();
  for (int i = tid; i < cnt; i += 256)
    atomicAdd(&hist[bucketArr[(size_t)b * BCAP + i] & 511], 1);
  __syncthreads();
  int a0 = hist[2 * tid], a1 = hist[2 * tid + 1];
  int s = a0 + a1;
  int lane = tid & 63, wid = tid >> 6;
  int inc = s;
  for (int d = 1; d < 64; d <<= 1) { int y = __shfl_up(inc, d, 64); if (lane >= d) inc += y; }
  if (lane == 63) wpart[wid] = inc;
  __syncthreads();
  int woff = 0;
  for (int q = 0; q < wid; q++) woff += wpart[q];
  int ex = woff + inc - s;
  offs[2 * tid] = ex; offs[2 * tid + 1] = ex + a0;
  curs[2 * tid] = ex; curs[2 * tid + 1] = ex + a0;
  __syncthreads();
  for (int i = tid; i < 512; i += 256) {
    int gn = b * 512 + i;
    if (gn < N_NODES) rp[gn] = base + offs[i];
  }
  for (int i = tid; i < cnt; i += 256) {
    int packed = bucketArr[(size_t)b * BCAP + i];
    int p = atomicAdd(&curs[packed & 511], 1);
    lsrc[p] = packed >> 9;
  }
  __syncthreads();
  for (int i = tid; i < cnt; i += 256) csr[base + i] = lsrc[i];
}

// ================= fp32 -> fp16 convert / weight prep =================

__global__ __launch_bounds__(256) void f32_to_f16_k(const float* __restrict__ in,
                                                    _Float16* __restrict__ out) {
  int i = blockIdx.x * 256 + threadIdx.x;
  float4 v0 = *(const float4*)(in + (size_t)i * 8);
  float4 v1 = *(const float4*)(in + (size_t)i * 8 + 4);
  half8 o;
  o[0] = (_Float16)v0.x; o[1] = (_Float16)v0.y; o[2] = (_Float16)v0.z; o[3] = (_Float16)v0.w;
  o[4] = (_Float16)v1.x; o[5] = (_Float16)v1.y; o[6] = (_Float16)v1.z; o[7] = (_Float16)v1.w;
  *(half8*)(out + (size_t)i * 8) = o;
}

// WT[n][k] = f16( k<128 ? Ws[k][n] : Wn[k-128][n] )
__global__ void build_wt_k(const float* __restrict__ Ws, const float* __restrict__ Wn,
                           _Float16* __restrict__ WT) {
  int n = blockIdx.x, k = threadIdx.x;
  float v = (k < 128) ? Ws[k * 128 + n] : Wn[(k - 128) * 128 + n];
  WT[n * 256 + k] = (_Float16)v;
}

__global__ void build_wct_k(const float* __restrict__ Wc, const float* __restrict__ bc,
                            _Float16* __restrict__ WcT, float* __restrict__ bcf) {
  int c = blockIdx.x, k = threadIdx.x;
  float v = (c < NCLS) ? Wc[k * NCLS + c] : 0.f;
  WcT[c * C + k] = (_Float16)v;
  if (k == 0) bcf[c] = (c < NCLS) ? bc[c] : 0.f;
}

// ================= fused layer: gather-mean -> LDS -> MFMA GEMM (-> classifier) ==========
// Per 32-row tile:
//  phase 1: mean-aggregate 32 nodes into LDS An (round-4 agg structure: 16 lanes/node,
//           4 edges/iter, unroll x2, shfl_xor(16,32) reduce; each wave does 8 nodes).
//  phase 2: weights-stationary GEMM relu([Xs|An] @ WT^T + b) -> cbuf (h tile, f16).
//           B frags (16x half8 = 64 VGPR) preloaded once per block lifetime.
//  phase 3: CLS=false -> store cbuf to out_h;  CLS=true -> 16x16x32 classifier
//           sub-GEMM from cbuf + WcT, write f32 logits directly.
// MFMA 32x32x16 C/D layout: col=lane&31, row=(q&3)+8*(q>>2)+4*(lane>>5)  [m74/m101].
// MFMA 16x16x32 C/D layout: col=lane&15, row=(lane>>4)*4+q  [m89/m91].

template <bool CLS>
__global__ __launch_bounds__(256, 3) void fused_sage_k(
    const _Float16* __restrict__ Xs, const int* __restrict__ rp, const int* __restrict__ csr,
    const _Float16* __restrict__ WT, const float* __restrict__ bias,
    const _Float16* __restrict__ WcT, const float* __restrict__ bcf,
    _Float16* __restrict__ out_h, float* __restrict__ out_cls) {
  __shared__ _Float16 An[32][132];   // stride 132 f16 = 66 dw: 2-way-ish on GEMM reads
  __shared__ _Float16 cbuf[32][136];
  int tid = threadIdx.x, lane = tid & 63, wid = tid >> 6;
  int l31 = lane & 31, l5 = lane >> 5;
  int g = lane >> 4, lr16 = lane & 15;   // gather: edge slot / feature chunk
  int col0 = wid * 32;

  // B frags resident for the block's whole lifetime (WT is 64KB, L2-hot)
  half8 b[16];
#pragma unroll
  for (int ks = 0; ks < 16; ks++)
    b[ks] = *(const half8*)(WT + (size_t)(col0 + l31) * 256 + ks * 16 + l5 * 8);
  float bcol = bias[col0 + l31];

  for (int t = blockIdx.x; t < NT_TILES; t += NB_FUSED) {
    int row0 = t * 32;

    // ---- phase 1: gather-mean 8 nodes per wave into An ----
#pragma unroll 1
    for (int ni = 0; ni < 8; ni++) {
      int nlocal = wid * 8 + ni;
      int node = row0 + nlocal;
      int beg = rp[node], end = rp[node + 1];
      float acc[8] = {}, acc2[8] = {};
      int j = beg;
      for (; j + 8 <= end; j += 8) {
        int e0 = csr[j + g];
        int e1 = csr[j + 4 + g];
        half8 v0 = *(const half8*)(Xs + (size_t)e0 * C + lr16 * 8);
        half8 v1 = *(const half8*)(Xs + (size_t)e1 * C + lr16 * 8);
#pragma unroll
        for (int q = 0; q < 8; q++) { acc[q] += (float)v0[q]; acc2[q] += (float)v1[q]; }
      }
      if (j + 4 <= end) {
        int e0 = csr[j + g];
        half8 v0 = *(const half8*)(Xs + (size_t)e0 * C + lr16 * 8);
#pragma unroll
        for (int q = 0; q < 8; q++) acc[q] += (float)v0[q];
        j += 4;
      }
      int rem = end - j;
      if (g < rem) {
        int e0 = csr[j + g];
        half8 v0 = *(const half8*)(Xs + (size_t)e0 * C + lr16 * 8);
#pragma unroll
        for (int q = 0; q < 8; q++) acc2[q] += (float)v0[q];
      }
#pragma unroll
      for (int q = 0; q < 8; q++) {
        float v = acc[q] + acc2[q];
        v += __shfl_xor(v, 16, 64);
        v += __shfl_xor(v, 32, 64);
        acc[q] = v;
      }
      if (g == 0) {
        float inv = 1.0f / fmaxf((float)(end - beg), 1.0f);
        half8 o;
#pragma unroll
        for (int q = 0; q < 8; q++) o[q] = (_Float16)(acc[q] * inv);
        *(half8*)(&An[nlocal][lr16 * 8]) = o;
      }
    }
    __syncthreads();

    // ---- phase 2: GEMM relu([Xs|An] @ WT^T + b) ----
    f32x16 acc = {};
    {
      half8 a[8];
#pragma unroll
      for (int ks = 0; ks < 8; ks++)
        a[ks] = *(const half8*)(Xs + (size_t)(row0 + l31) * C + ks * 16 + l5 * 8);
#pragma unroll
      for (int ks = 0; ks < 8; ks++)
        acc = __builtin_amdgcn_mfma_f32_32x32x16_f16(a[ks], b[ks], acc, 0, 0, 0);
#pragma unroll
      for (int ks = 0; ks < 8; ks++)
        a[ks] = *(const half8*)(&An[l31][ks * 16 + l5 * 8]);
#pragma unroll
      for (int ks = 0; ks < 8; ks++)
        acc = __builtin_amdgcn_mfma_f32_32x32x16_f16(a[ks], b[ks + 8], acc, 0, 0, 0);
    }
#pragma unroll
    for (int q = 0; q < 16; q++) {
      int row = (q & 3) + 8 * (q >> 2) + 4 * l5;
      float v = fmaxf(acc[q] + bcol, 0.f);
      cbuf[row][col0 + l31] = (_Float16)v;
    }
    __syncthreads();

    if (!CLS) {
      // ---- phase 3a: store h tile ----
#pragma unroll
      for (int p = 0; p < 2; p++) {
        int chunk = tid + p * 256;
        int r = chunk >> 4, cg = chunk & 15;
        half8 v = *(const half8*)&cbuf[r][cg * 8];
        *(half8*)(out_h + (size_t)(row0 + r) * C + cg * 8) = v;
      }
    } else {
      // ---- phase 3b: classifier h2 @ WcT^T + bc -> f32 (waves 0,1) ----
      if (wid < 2) {
        f32x4 cacc[3] = {};
        int lk = lane >> 4;
#pragma unroll
        for (int ks = 0; ks < 4; ks++) {
          half8 a = *(const half8*)(&cbuf[wid * 16 + lr16][ks * 32 + lk * 8]);
#pragma unroll
          for (int nf = 0; nf < 3; nf++) {
            half8 bf = *(const half8*)(WcT + (size_t)(nf * 16 + lr16) * C + ks * 32 + lk * 8);
            cacc[nf] = __builtin_amdgcn_mfma_f32_16x16x32_f16(a, bf, cacc[nf], 0, 0, 0);
          }
        }
#pragma unroll
        for (int nf = 0; nf < 3; nf++) {
          int c = nf * 16 + lr16;
          if (c < NCLS) {
#pragma unroll
            for (int q = 0; q < 4; q++) {
              int r = row0 + wid * 16 + lk * 4 + q;
              out_cls[(size_t)r * NCLS + c] = cacc[nf][q] + bcf[c];
            }
          }
        }
      }
    }
    __syncthreads();  // protect An/cbuf before next tile iteration
  }
}

// ================= launch =================

extern "C" void kernel_launch(void* const* d_in, const int* in_sizes, int n_in,
                              void* d_out, int out_size, void* d_ws, size_t ws_size,
                              hipStream_t stream) {
  (void)in_sizes; (void)n_in; (void)out_size; (void)ws_size;
  const float* x   = (const float*)d_in[0];
  const int*   ei  = (const int*)d_in[1];
  const float* Ws1 = (const float*)d_in[2];
  const float* Wn1 = (const float*)d_in[3];
  const float* b1  = (const float*)d_in[4];
  const float* Ws2 = (const float*)d_in[5];
  const float* Wn2 = (const float*)d_in[6];
  const float* b2  = (const float*)d_in[7];
  const float* Wc  = (const float*)d_in[8];
  const float* bc  = (const float*)d_in[9];
  const int* src = ei;
  const int* dst = ei + N_EDGES;

  char* ws = (char*)d_ws;
  size_t off = 0;
  auto alloc = [&](size_t bytes) {
    void* p = ws + off;
    off = (off + bytes + 255) & ~(size_t)255;
    return p;
  };
  int*      bucket_cnt  = (int*)alloc((size_t)NBUCK * 4);
  int*      bucket_base = (int*)alloc((size_t)(NBUCK + 1) * 4);
  int*      bucketArr   = (int*)alloc((size_t)NBUCK * BCAP * 4);
  int*      rp          = (int*)alloc((size_t)(N_NODES + 1) * 4);
  int*      csr         = (int*)alloc((size_t)N_EDGES * 4);
  _Float16* hA          = (_Float16*)alloc((size_t)N_NODES * C * 2);  // x (f16)
  _Float16* hC          = (_Float16*)alloc((size_t)N_NODES * C * 2);  // h1
  _Float16* WT1         = (_Float16*)alloc((size_t)C * 256 * 2);
  _Float16* WT2         = (_Float16*)alloc((size_t)C * 256 * 2);
  _Float16* WcT         = (_Float16*)alloc((size_t)48 * C * 2);
  float*    bcf         = (float*)alloc(48 * 4);
  float* outf = (float*)d_out;

  // CSR build (bucketed counting sort)
  hipMemsetAsync(bucket_cnt, 0, (size_t)NBUCK * 4, stream);
  bucket_scatter_k<<<(N_EDGES + 4095) / 4096, 256, 0, stream>>>(src, dst, bucket_cnt, bucketArr);
  bucket_scan_k<<<1, 256, 0, stream>>>(bucket_cnt, bucket_base, rp);
  bucket_sort_k<<<NBUCK, 256, 0, stream>>>(bucketArr, bucket_cnt, bucket_base, rp, csr);

  // weight prep + x conversion
  build_wt_k<<<C, 256, 0, stream>>>(Ws1, Wn1, WT1);
  build_wt_k<<<C, 256, 0, stream>>>(Ws2, Wn2, WT2);
  build_wct_k<<<48, C, 0, stream>>>(Wc, bc, WcT, bcf);
  f32_to_f16_k<<<(N_NODES * C / 8) / 256, 256, 0, stream>>>(x, hA);

  // layer 1 (fused gather + GEMM) : hA -> hC
  fused_sage_k<false><<<NB_FUSED, 256, 0, stream>>>(hA, rp, csr, WT1, b1,
                                                    nullptr, nullptr, hC, nullptr);
  // layer 2 + classifier (fused)  : hC -> logits
  fused_sage_k<true><<<NB_FUSED, 256, 0, stream>>>(hC, rp, csr, WT2, b2,
                                                   WcT, bcf, nullptr, outf);
}

// Round 8
// 363.837 us; speedup vs baseline: 1.2002x; 1.1369x over previous
//
#include <hip/hip_runtime.h>

#define N_NODES 100000
#define N_EDGES 1600000
#define C 128
#define NCLS 40
#define NBUCK 196   // ceil(100000/512)
#define BCAP 12288  // per-bucket edge capacity (mean 8192, +45 sigma)
#define NT_TILES 3125  // 100000/32

typedef _Float16 half8 __attribute__((ext_vector_type(8)));
typedef float f32x4 __attribute__((ext_vector_type(4)));
typedef float f32x16 __attribute__((ext_vector_type(16)));

// ================= bucketed CSR build =================

__global__ __launch_bounds__(256) void bucket_scatter_k(const int* __restrict__ src,
    const int* __restrict__ dst, int* __restrict__ bucket_cnt, int* __restrict__ bucketArr) {
  __shared__ int lh[NBUCK], lbase[NBUCK], lcur[NBUCK];
  int tid = threadIdx.x;
  for (int i = tid; i < NBUCK; i += 256) { lh[i] = 0; lcur[i] = 0; }
  __syncthreads();
  int base = blockIdx.x * 4096;
  int bmax = min(base + 4096, N_EDGES);
  int dreg[16];
  int nk = 0;
  for (int e = base + tid; e < bmax; e += 256) dreg[nk++] = dst[e];
  for (int k = 0; k < nk; k++) atomicAdd(&lh[dreg[k] >> 9], 1);
  __syncthreads();
  for (int i = tid; i < NBUCK; i += 256)
    lbase[i] = lh[i] ? atomicAdd(&bucket_cnt[i], lh[i]) : 0;
  __syncthreads();
  nk = 0;
  for (int e = base + tid; e < bmax; e += 256) {
    int d = dreg[nk++];
    int b = d >> 9, loc = d & 511;
    int p = lbase[b] + atomicAdd(&lcur[b], 1);
    if (p < BCAP) bucketArr[(size_t)b * BCAP + p] = (src[e] << 9) | loc;
  }
}

// One block per bucket. Computes its own bucket_base via a local 196-entry scan
// (drops the separate scan dispatch), then LDS counting-sort + dense csr/rp writes.
__global__ __launch_bounds__(256) void bucket_sort_k(const int* __restrict__ bucketArr,
    const int* __restrict__ bucket_cnt, int* __restrict__ rp, int* __restrict__ csr) {
  __shared__ int pref[NBUCK + 1];
  __shared__ int hist[512], offs[512], curs[512];
  __shared__ int wpart[4];
  __shared__ int lsrc[BCAP];
  int b = blockIdx.x, tid = threadIdx.x;
  int lane = tid & 63, wid = tid >> 6;

  // local exclusive scan of all bucket counts (196 ints)
  {
    int v = (tid < NBUCK) ? min(bucket_cnt[tid], BCAP) : 0;
    int inc = v;
    for (int d = 1; d < 64; d <<= 1) { int y = __shfl_up(inc, d, 64); if (lane >= d) inc += y; }
    if (lane == 63) wpart[wid] = inc;
    __syncthreads();
    int woff = 0;
    for (int q = 0; q < wid; q++) woff += wpart[q];
    int ex = woff + inc - v;
    if (tid < NBUCK) pref[tid] = ex;
    if (tid == NBUCK - 1) pref[NBUCK] = ex + v;
    __syncthreads();
  }
  int base = pref[b];
  int cnt = min(bucket_cnt[b], BCAP);
  if (b == 0 && tid == 0) rp[N_NODES] = pref[NBUCK];
  __syncthreads();

  for (int i = tid; i < 512; i += 256) hist[i] = 0;
  __syncthreads();
  for (int i = tid; i < cnt; i += 256)
    atomicAdd(&hist[bucketArr[(size_t)b * BCAP + i] & 511], 1);
  __syncthreads();
  int a0 = hist[2 * tid], a1 = hist[2 * tid + 1];
  int s = a0 + a1;
  int inc = s;
  for (int d = 1; d < 64; d <<= 1) { int y = __shfl_up(inc, d, 64); if (lane >= d) inc += y; }
  if (lane == 63) wpart[wid] = inc;
  __syncthreads();
  int woff = 0;
  for (int q = 0; q < wid; q++) woff += wpart[q];
  int ex = woff + inc - s;
  offs[2 * tid] = ex; offs[2 * tid + 1] = ex + a0;
  curs[2 * tid] = ex; curs[2 * tid + 1] = ex + a0;
  __syncthreads();
  for (int i = tid; i < 512; i += 256) {
    int gn = b * 512 + i;
    if (gn < N_NODES) rp[gn] = base + offs[i];
  }
  for (int i = tid; i < cnt; i += 256) {
    int packed = bucketArr[(size_t)b * BCAP + i];
    int p = atomicAdd(&curs[packed & 511], 1);
    lsrc[p] = packed >> 9;
  }
  __syncthreads();
  for (int i = tid; i < cnt; i += 256) csr[base + i] = lsrc[i];
}

// ================= fp32 -> fp16 convert / merged weight prep =================

__global__ __launch_bounds__(256) void f32_to_f16_k(const float* __restrict__ in,
                                                    _Float16* __restrict__ out) {
  int i = blockIdx.x * 256 + threadIdx.x;
  float4 v0 = *(const float4*)(in + (size_t)i * 8);
  float4 v1 = *(const float4*)(in + (size_t)i * 8 + 4);
  half8 o;
  o[0] = (_Float16)v0.x; o[1] = (_Float16)v0.y; o[2] = (_Float16)v0.z; o[3] = (_Float16)v0.w;
  o[4] = (_Float16)v1.x; o[5] = (_Float16)v1.y; o[6] = (_Float16)v1.z; o[7] = (_Float16)v1.w;
  *(half8*)(out + (size_t)i * 8) = o;
}

// blocks 0-127: WT1; 128-255: WT2; 256-303: WcT + bcf
__global__ void build_weights_k(const float* __restrict__ Ws1, const float* __restrict__ Wn1,
                                const float* __restrict__ Ws2, const float* __restrict__ Wn2,
                                const float* __restrict__ Wc, const float* __restrict__ bc,
                                _Float16* __restrict__ WT1, _Float16* __restrict__ WT2,
                                _Float16* __restrict__ WcT, float* __restrict__ bcf) {
  int b = blockIdx.x, k = threadIdx.x;
  if (b < 128) {
    float v = (k < 128) ? Ws1[k * 128 + b] : Wn1[(k - 128) * 128 + b];
    WT1[b * 256 + k] = (_Float16)v;
  } else if (b < 256) {
    int n = b - 128;
    float v = (k < 128) ? Ws2[k * 128 + n] : Wn2[(k - 128) * 128 + n];
    WT2[n * 256 + k] = (_Float16)v;
  } else if (k < 128) {
    int c = b - 256;
    float v = (c < NCLS) ? Wc[k * NCLS + c] : 0.f;
    WcT[c * C + k] = (_Float16)v;
    if (k == 0) bcf[c] = (c < NCLS) ? bc[c] : 0.f;
  }
}

// ================= mean aggregation =================
// wave = 1 node; 16 lanes/node pattern: 4 edge slots (g) x 16 feature chunks (lr).
// 16 edges in flight per iter via 4 independent f16 packed accumulator sets
// (v_pk_add_f16), combined in f32 at the end (error ~<3e-4 after /deg).

__global__ __launch_bounds__(256) void agg_mean_h_k(const _Float16* __restrict__ feat,
    const int* __restrict__ rp, const int* __restrict__ csr, _Float16* __restrict__ out) {
  int w = threadIdx.x >> 6;
  int node = blockIdx.x * 4 + w;
  int lane = threadIdx.x & 63;
  int g = lane >> 4, lr = lane & 15;
  int beg = rp[node], end = rp[node + 1];
  half8 h0 = {}, h1 = {}, h2 = {}, h3 = {};
  int j = beg;
  for (; j + 16 <= end; j += 16) {
    int e0 = csr[j + g];
    int e1 = csr[j + 4 + g];
    int e2 = csr[j + 8 + g];
    int e3 = csr[j + 12 + g];
    half8 v0 = *(const half8*)(feat + (size_t)e0 * C + lr * 8);
    half8 v1 = *(const half8*)(feat + (size_t)e1 * C + lr * 8);
    half8 v2 = *(const half8*)(feat + (size_t)e2 * C + lr * 8);
    half8 v3 = *(const half8*)(feat + (size_t)e3 * C + lr * 8);
    h0 += v0; h1 += v1; h2 += v2; h3 += v3;
  }
  for (; j + 4 <= end; j += 4) {
    int e0 = csr[j + g];
    half8 v0 = *(const half8*)(feat + (size_t)e0 * C + lr * 8);
    h0 += v0;
  }
  int rem = end - j;
  if (g < rem) {
    int e0 = csr[j + g];
    half8 v0 = *(const half8*)(feat + (size_t)e0 * C + lr * 8);
    h1 += v0;
  }
  float acc[8];
#pragma unroll
  for (int q = 0; q < 8; q++)
    acc[q] = ((float)h0[q] + (float)h1[q]) + ((float)h2[q] + (float)h3[q]);
#pragma unroll
  for (int q = 0; q < 8; q++) {
    float v = acc[q];
    v += __shfl_xor(v, 16, 64);
    v += __shfl_xor(v, 32, 64);
    acc[q] = v;
  }
  if (g == 0) {
    float inv = 1.0f / fmaxf((float)(end - beg), 1.0f);
    half8 o;
#pragma unroll
    for (int q = 0; q < 8; q++) o[q] = (_Float16)(acc[q] * inv);
    *(half8*)(out + (size_t)node * C + lr * 8) = o;
  }
}

// ================= weights-stationary fused SAGE GEMM (+ optional classifier) ==========
// out = relu( [Xs|Xn] @ WT^T + b ). Wave = fixed 32-col slice, B frags resident;
// grid-stride over 32-row tiles. CLS=true: h2 stays in LDS, classifier sub-GEMM
// (16x16x32, waves 0-1) writes f32 logits; h2 never touches global memory.
// MFMA 32x32x16 C/D: col=lane&31, row=(q&3)+8*(q>>2)+4*(lane>>5)  [m74/m101].
// MFMA 16x16x32 C/D: col=lane&15, row=(lane>>4)*4+q  [m89/m91].

template <bool CLS>
__global__ __launch_bounds__(256) void sage_gemm_ws_k(
    const _Float16* __restrict__ Xs, const _Float16* __restrict__ Xn,
    const _Float16* __restrict__ WT, const float* __restrict__ bias,
    const _Float16* __restrict__ WcT, const float* __restrict__ bcf,
    _Float16* __restrict__ out_h, float* __restrict__ out_cls) {
  __shared__ _Float16 cbuf[32][136];
  int tid = threadIdx.x, lane = tid & 63, wid = tid >> 6;
  int l31 = lane & 31, l5 = lane >> 5;
  int col0 = wid * 32;

  half8 b[16];
#pragma unroll
  for (int ks = 0; ks < 16; ks++)
    b[ks] = *(const half8*)(WT + (size_t)(col0 + l31) * 256 + ks * 16 + l5 * 8);
  float bcol = bias[col0 + l31];

  for (int t = blockIdx.x; t < NT_TILES; t += gridDim.x) {
    size_t row0 = (size_t)t * 32;
    half8 a[16];
#pragma unroll
    for (int ks = 0; ks < 8; ks++) {
      a[ks]     = *(const half8*)(Xs + (row0 + l31) * C + ks * 16 + l5 * 8);
      a[ks + 8] = *(const half8*)(Xn + (row0 + l31) * C + ks * 16 + l5 * 8);
    }
    f32x16 acc = {};
#pragma unroll
    for (int ks = 0; ks < 16; ks++)
      acc = __builtin_amdgcn_mfma_f32_32x32x16_f16(a[ks], b[ks], acc, 0, 0, 0);

    __syncthreads();  // cbuf reuse guard
#pragma unroll
    for (int q = 0; q < 16; q++) {
      int row = (q & 3) + 8 * (q >> 2) + 4 * l5;
      float v = fmaxf(acc[q] + bcol, 0.f);
      cbuf[row][col0 + l31] = (_Float16)v;
    }
    __syncthreads();

    if (!CLS) {
#pragma unroll
      for (int p = 0; p < 2; p++) {
        int chunk = tid + p * 256;
        int r = chunk >> 4, cg = chunk & 15;
        half8 v = *(const half8*)&cbuf[r][cg * 8];
        *(half8*)(out_h + (row0 + r) * C + cg * 8) = v;
      }
    } else if (wid < 2) {
      int lr16 = lane & 15, lk = lane >> 4;
      f32x4 cacc[3] = {};
#pragma unroll
      for (int ks = 0; ks < 4; ks++) {
        half8 av = *(const half8*)(&cbuf[wid * 16 + lr16][ks * 32 + lk * 8]);
#pragma unroll
        for (int nf = 0; nf < 3; nf++) {
          half8 bf = *(const half8*)(WcT + (size_t)(nf * 16 + lr16) * C + ks * 32 + lk * 8);
          cacc[nf] = __builtin_amdgcn_mfma_f32_16x16x32_f16(av, bf, cacc[nf], 0, 0, 0);
        }
      }
#pragma unroll
      for (int nf = 0; nf < 3; nf++) {
        int c = nf * 16 + lr16;
        if (c < NCLS) {
#pragma unroll
          for (int q = 0; q < 4; q++) {
            size_t r = row0 + wid * 16 + lk * 4 + q;
            out_cls[r * NCLS + c] = cacc[nf][q] + bcf[c];
          }
        }
      }
    }
  }
}

// ================= launch =================

extern "C" void kernel_launch(void* const* d_in, const int* in_sizes, int n_in,
                              void* d_out, int out_size, void* d_ws, size_t ws_size,
                              hipStream_t stream) {
  (void)in_sizes; (void)n_in; (void)out_size; (void)ws_size;
  const float* x   = (const float*)d_in[0];
  const int*   ei  = (const int*)d_in[1];
  const float* Ws1 = (const float*)d_in[2];
  const float* Wn1 = (const float*)d_in[3];
  const float* b1  = (const float*)d_in[4];
  const float* Ws2 = (const float*)d_in[5];
  const float* Wn2 = (const float*)d_in[6];
  const float* b2  = (const float*)d_in[7];
  const float* Wc  = (const float*)d_in[8];
  const float* bc  = (const float*)d_in[9];
  const int* src = ei;
  const int* dst = ei + N_EDGES;

  char* ws = (char*)d_ws;
  size_t off = 0;
  auto alloc = [&](size_t bytes) {
    void* p = ws + off;
    off = (off + bytes + 255) & ~(size_t)255;
    return p;
  };
  int*      bucket_cnt  = (int*)alloc((size_t)NBUCK * 4);
  int*      bucketArr   = (int*)alloc((size_t)NBUCK * BCAP * 4);
  int*      rp          = (int*)alloc((size_t)(N_NODES + 1) * 4);
  int*      csr         = (int*)alloc((size_t)N_EDGES * 4);
  _Float16* hA          = (_Float16*)alloc((size_t)N_NODES * C * 2);  // x (f16)
  _Float16* hB          = (_Float16*)alloc((size_t)N_NODES * C * 2);  // agg outputs
  _Float16* hC          = (_Float16*)alloc((size_t)N_NODES * C * 2);  // h1
  _Float16* WT1         = (_Float16*)alloc((size_t)C * 256 * 2);
  _Float16* WT2         = (_Float16*)alloc((size_t)C * 256 * 2);
  _Float16* WcT         = (_Float16*)alloc((size_t)48 * C * 2);
  float*    bcf         = (float*)alloc(48 * 4);
  float* outf = (float*)d_out;

  // CSR build
  hipMemsetAsync(bucket_cnt, 0, (size_t)NBUCK * 4, stream);
  bucket_scatter_k<<<(N_EDGES + 4095) / 4096, 256, 0, stream>>>(src, dst, bucket_cnt, bucketArr);
  bucket_sort_k<<<NBUCK, 256, 0, stream>>>(bucketArr, bucket_cnt, rp, csr);

  // weight prep + x conversion
  build_weights_k<<<304, 256, 0, stream>>>(Ws1, Wn1, Ws2, Wn2, Wc, bc, WT1, WT2, WcT, bcf);
  f32_to_f16_k<<<(N_NODES * C / 8) / 256, 256, 0, stream>>>(x, hA);

  // layer 1
  agg_mean_h_k<<<N_NODES / 4, 256, 0, stream>>>(hA, rp, csr, hB);
  sage_gemm_ws_k<false><<<782, 256, 0, stream>>>(hA, hB, WT1, b1, nullptr, nullptr, hC, nullptr);
  // layer 2 + fused classifier (h2 never leaves LDS)
  agg_mean_h_k<<<N_NODES / 4, 256, 0, stream>>>(hC, rp, csr, hB);
  sage_gemm_ws_k<true><<<782, 256, 0, stream>>>(hC, hB, WT2, b2, WcT, bcf, nullptr, outf);
}